// Round 6
// baseline (364.286 us; speedup 1.0000x reference)
//
#include <hip/hip_runtime.h>

#define D_DIM 1024
#define H_DIM 1024
#define E_NUM 8
#define BM 128
#define BN 128        // in interleaved v/g column space (2*H per expert)
#define BK 64
#define NT (D_DIM / BK)
#define CAP 5120      // per-expert bucket capacity (mean 4096, sigma ~60; >17 sigma)
#define MT (CAP / BM)                    // 40 m-tiles per expert
#define NTL ((2 * H_DIM) / BN)           // 16 n-tiles per expert
#define RT_TOK 32     // tokens per router block

typedef __attribute__((ext_vector_type(8))) _Float16 h8v;
typedef __attribute__((ext_vector_type(4))) float f4v;

__device__ __forceinline__ unsigned short f2h(float f) {
  union { _Float16 h; unsigned short u; } c;
  c.h = (_Float16)f;  // v_cvt_f16_f32, RNE
  return c.u;
}

// async 16B global->LDS DMA; LDS dest = wave-uniform base + lane*16
__device__ __forceinline__ void gl2lds16(const void* g, void* l) {
  __builtin_amdgcn_global_load_lds(
      (const __attribute__((address_space(1))) unsigned int*)g,
      (__attribute__((address_space(3))) unsigned int*)l, 16, 0, 0);
}

// generic (flat) LDS pointer -> 32-bit LDS byte offset for raw ds_read asm
__device__ __forceinline__ unsigned ldsaddr(const void* p) {
  return (unsigned)(unsigned long long)(const __attribute__((address_space(3))) void*)p;
}

// ---------------- phase 0: W [E][D][H] fp32 -> Wc [E][2H][D] fp16 interleaved ----
// n-row mapping: n = (h>>4)*32 + mat*16 + (h&15)  (mat 0=Wv, 1=Wg)
__global__ __launch_bounds__(256) void transpose_w_kernel(
    const float* __restrict__ Wv, const float* __restrict__ Wg,
    unsigned short* __restrict__ Wc) {
  __shared__ float tile[64][65];  // pad 65: 2-way max on both phases
  int z = blockIdx.z;             // 0..15: bit0 = which matrix, rest = expert
  const float* W = (z & 1) ? Wg : Wv;
  int mat = z & 1;
  int e = z >> 1;
  int h0 = blockIdx.x * 64, d0 = blockIdx.y * 64;
  const float* Wp = W + (size_t)e * D_DIM * H_DIM;
  unsigned short* Wcp = Wc + (size_t)e * (2 * H_DIM) * D_DIM;
  int t = threadIdx.x;
#pragma unroll
  for (int j = 0; j < 4; j++) {  // 1024 float4 loads, 4/thread
    int id = t + 256 * j;
    int dd = id >> 4, hc = id & 15;
    float4 v = *(const float4*)(Wp + (size_t)(d0 + dd) * H_DIM + h0 + hc * 4);
    tile[dd][hc * 4 + 0] = v.x;
    tile[dd][hc * 4 + 1] = v.y;
    tile[dd][hc * 4 + 2] = v.z;
    tile[dd][hc * 4 + 3] = v.w;
  }
  __syncthreads();
#pragma unroll
  for (int j = 0; j < 2; j++) {  // 512 uint4 (8-half) stores, 2/thread
    int id = t + 256 * j;
    int h_ = id >> 3, dc = id & 7;
    unsigned short tmp[8];
#pragma unroll
    for (int k = 0; k < 8; k++) tmp[k] = f2h(tile[dc * 8 + k][h_]);
    int hg = h0 + h_;
    int ng = ((hg >> 4) << 5) | (mat << 4) | (hg & 15);
    *(uint4*)(Wcp + (size_t)ng * D_DIM + d0 + dc * 8) = *(uint4*)tmp;
  }
}

// ---------------- phase 1: router (fp32 exact top-2) + fused x->fp16 convert ----
// counts[] padded: expert e at counts[e*32] (128 B apart -> no line contention).
__global__ __launch_bounds__(256) void router_kernel(
    const float4* __restrict__ x4, const float4* __restrict__ gw4,
    const float* __restrict__ gb, int* __restrict__ counts,
    int* __restrict__ bucket, float* __restrict__ scoreB,
    int* __restrict__ slotOf, ushort4* __restrict__ xh4, int B) {
  __shared__ float4 gwS[E_NUM * 256];  // 32 KB: all 8 expert rows
  __shared__ short eSelS[RT_TOK][2];
  __shared__ float sSelS[RT_TOK][2];
  __shared__ int lCnt[E_NUM], lBase[E_NUM];
  __shared__ unsigned char lOff[RT_TOK][2];
  int tid = threadIdx.x;
  for (int i = tid; i < E_NUM * 256; i += 256) gwS[i] = gw4[i];
  if (tid < E_NUM) lCnt[tid] = 0;
  __syncthreads();
  int wid = tid >> 6, lane = tid & 63;
  for (int rep = 0; rep < RT_TOK / 4; rep++) {
    int t = wid * (RT_TOK / 4) + rep;
    int b = blockIdx.x * RT_TOK + t;
    float acc[E_NUM];
#pragma unroll
    for (int e = 0; e < E_NUM; e++) acc[e] = 0.0f;
#pragma unroll
    for (int i = 0; i < 4; i++) {
      float4 xv = x4[(size_t)b * 256 + i * 64 + lane];
      ushort4 o;
      o.x = f2h(xv.x); o.y = f2h(xv.y); o.z = f2h(xv.z); o.w = f2h(xv.w);
      xh4[(size_t)b * 256 + i * 64 + lane] = o;  // fused fp16 convert
#pragma unroll
      for (int e = 0; e < E_NUM; e++) {
        float4 w = gwS[e * 256 + i * 64 + lane];
        acc[e] += xv.x * w.x + xv.y * w.y + xv.z * w.z + xv.w * w.w;
      }
    }
#pragma unroll
    for (int e = 0; e < E_NUM; e++) {
#pragma unroll
      for (int off = 32; off > 0; off >>= 1) acc[e] += __shfl_down(acc[e], off);
    }
    if (lane == 0) {
      float l[E_NUM];
#pragma unroll
      for (int e = 0; e < E_NUM; e++) l[e] = acc[e] + gb[e];
      int i0 = 0;
#pragma unroll
      for (int e = 1; e < E_NUM; e++) if (l[e] > l[i0]) i0 = e;
      int i1 = (i0 == 0) ? 1 : 0;
#pragma unroll
      for (int e = 0; e < E_NUM; e++) if (e != i0 && l[e] > l[i1]) i1 = e;
      float mx = l[i0];
      float denom = 0.0f;
#pragma unroll
      for (int e = 0; e < E_NUM; e++) denom += __expf(l[e] - mx);
      eSelS[t][0] = (short)i0; sSelS[t][0] = 1.0f / denom;
      eSelS[t][1] = (short)i1; sSelS[t][1] = __expf(l[i1] - mx) / denom;
    }
  }
  __syncthreads();
  if (tid < RT_TOK) {
    lOff[tid][0] = (unsigned char)atomicAdd(&lCnt[eSelS[tid][0]], 1);
    lOff[tid][1] = (unsigned char)atomicAdd(&lCnt[eSelS[tid][1]], 1);
  }
  __syncthreads();
  if (tid < E_NUM) lBase[tid] = atomicAdd(&counts[tid * 32], lCnt[tid]);
  __syncthreads();
  if (tid < RT_TOK) {
    int b = blockIdx.x * RT_TOK + tid;
#pragma unroll
    for (int j = 0; j < 2; j++) {
      int e = eSelS[tid][j];
      int pos = lBase[e] + lOff[tid][j];
      if (pos < CAP) {
        int slot = e * CAP + pos;
        bucket[slot] = b;
        scoreB[slot] = sSelS[tid][j];
        slotOf[b * 2 + j] = slot;
      }
    }
  }
}

// ---------------- phase 2: grouped GEMM (interleaved v/g) + SwiGLU ----------------
// R6: 128x128x64 tile, 4 waves (2M x 2N), 65.5 KB LDS double-buffer ->
// *** 2 blocks/CU ***. R5 proved the 256² 1-block/CU kernel is schedule-
// latency bound (FETCH -29MB with dur unchanged; neither LDS port nor MFMA
// saturated at 40% util). Cross-block overlap (m114) replaces intra-block
// phase engineering: while one block drains vmcnt/barrier, the other owns
// the MFMA pipe. Smaller tile also kills ALL fragment re-reads: 16 asm
// ds_read_b128 per wave per tile (af[4][2]+bf[4][2] = 64 VGPR live), one
// barrier + two-stage counted lgkm per K-tile.
// Verified ingredients kept: interleaved Wc (SwiGLU in-lane), lane-constant
// XOR swizzle (0 conflicts), inline-asm ds_reads (no compiler vmcnt(0)),
// sched_barrier after each lgkm (rule #18), setprio around MFMA, XCD-
// bijective block swizzle (e = o&7; m fastest within expert).

#define DSR(dst, areg, IMM)                                                   \
  asm volatile("ds_read_b128 %0, %1 offset:%c2"                               \
               : "=v"(dst) : "v"(areg), "i"(IMM))

// 16 reads of one K-tile: s=0 frags first (8), then s=1 (8)
#define RD16(CB) do {                                                         \
    DSR(af[0][0], aA0, (CB) * 16384 + 0);                                     \
    DSR(af[1][0], aA0, (CB) * 16384 + 2048);                                  \
    DSR(af[2][0], aA0, (CB) * 16384 + 4096);                                  \
    DSR(af[3][0], aA0, (CB) * 16384 + 6144);                                  \
    DSR(bf[0][0], bB0, (CB) * 16384 + 0);                                     \
    DSR(bf[1][0], bB0, (CB) * 16384 + 2048);                                  \
    DSR(bf[2][0], bB0, (CB) * 16384 + 4096);                                  \
    DSR(bf[3][0], bB0, (CB) * 16384 + 6144);                                  \
    DSR(af[0][1], aA1, (CB) * 16384 + 0);                                     \
    DSR(af[1][1], aA1, (CB) * 16384 + 2048);                                  \
    DSR(af[2][1], aA1, (CB) * 16384 + 4096);                                  \
    DSR(af[3][1], aA1, (CB) * 16384 + 6144);                                  \
    DSR(bf[0][1], bB1, (CB) * 16384 + 0);                                     \
    DSR(bf[1][1], bB1, (CB) * 16384 + 2048);                                  \
    DSR(bf[2][1], bB1, (CB) * 16384 + 4096);                                  \
    DSR(bf[3][1], bB1, (CB) * 16384 + 6144);                                  \
  } while (0)

// 16 MFMAs of one K=32 slice S
#define MFMA16(S) do {                                                        \
    _Pragma("unroll") for (int m = 0; m < 4; m++) {                           \
      _Pragma("unroll") for (int n = 0; n < 4; n++) {                         \
        acc[m][n] = __builtin_amdgcn_mfma_f32_16x16x32_f16(                   \
            af[m][S], bf[n][S], acc[m][n], 0, 0, 0);                          \
      }                                                                       \
    }                                                                         \
  } while (0)

// stage one full K-tile (A 16 KB + B 16 KB) into buffer NB: 8 DMAs/thread
#define STG8(NB) do {                                                         \
    gl2lds16(pA[0], (char*)As + (NB) * 16384 + 0 * 4096 + dstB);              \
    gl2lds16(pA[1], (char*)As + (NB) * 16384 + 1 * 4096 + dstB);              \
    gl2lds16(pA[2], (char*)As + (NB) * 16384 + 2 * 4096 + dstB);              \
    gl2lds16(pA[3], (char*)As + (NB) * 16384 + 3 * 4096 + dstB);              \
    gl2lds16(pB[0], (char*)Bs + (NB) * 16384 + 0 * 4096 + dstB);              \
    gl2lds16(pB[1], (char*)Bs + (NB) * 16384 + 1 * 4096 + dstB);              \
    gl2lds16(pB[2], (char*)Bs + (NB) * 16384 + 2 * 4096 + dstB);              \
    gl2lds16(pB[3], (char*)Bs + (NB) * 16384 + 3 * 4096 + dstB);              \
  } while (0)

#define PH_BAR() __builtin_amdgcn_s_barrier()
#define LGKM(N) do {                                                          \
    asm volatile("s_waitcnt lgkmcnt(" #N ")" ::: "memory");                   \
    __builtin_amdgcn_sched_barrier(0);                                        \
  } while (0)
#define VMW(N) asm volatile("s_waitcnt vmcnt(" #N ")" ::: "memory")
#define PRIO1() __builtin_amdgcn_s_setprio(1)
#define PRIO0() __builtin_amdgcn_s_setprio(0)

// one K-tile: read 16 frags; stage next tile; two-stage lgkm; ONE barrier.
// WAR safety: all waves passed LGKM(0) on buf CB^1 before the PREVIOUS
// barrier, so STG8 into CB^1 here cannot race those reads.
#define TILE128(CB, STG) do {                                                 \
    RD16(CB);                                                                 \
    if (STG) STG8((CB) ^ 1);                                                  \
    LGKM(8); PRIO1(); MFMA16(0); PRIO0();                                     \
    LGKM(0); PRIO1(); MFMA16(1); PRIO0();                                     \
    if (STG) VMW(0);  /* next-tile DMAs landed (issued ~1 tile ago) */        \
    PH_BAR();                                                                 \
    if (STG) {                                                                \
      _Pragma("unroll") for (int i = 0; i < 4; i++) { pA[i] += BK; pB[i] += BK; } \
    }                                                                         \
  } while (0)

template <bool USE_PARTIAL>
__global__ __launch_bounds__(256, 2) void moe_gemm_kernel(
    const unsigned short* __restrict__ xh, const unsigned short* __restrict__ Wc,
    const int* __restrict__ counts, const int* __restrict__ bucket,
    const float* __restrict__ scoreB, _Float16* __restrict__ partial,
    float* __restrict__ out, int B) {
  // XCD-bijective swizzle: 5120 = 8 XCDs x 640. XCD k owns expert k; within
  // an expert, m sweeps fastest (40 consecutive blocks share one 256 KB
  // B panel, L2-hot).
  int o = blockIdx.x;
  int e = o & 7;
  int r = o >> 3;             // 0..639
  int m0 = (r % MT) * BM;
  int nt_ = r / MT;           // 0..15
  int n0 = nt_ * BN;
  int cnt = counts[e * 32];
  if (m0 >= cnt) return;

  __shared__ unsigned short As[2][BM * BK];  // 32 KB
  __shared__ unsigned short Bs[2][BN * BK];  // 32 KB
  __shared__ int tokS[BM];
  __shared__ float scS[BM];

  int tid = threadIdx.x;
  if (tid < BM) {
    int gr = m0 + tid;
    bool vld = gr < cnt;
    tokS[tid] = vld ? bucket[e * CAP + gr] : 0;
    scS[tid] = vld ? scoreB[e * CAP + gr] : 0.0f;  // padded rows contribute 0
  }
  __syncthreads();

  int wid = tid >> 6, lane = tid & 63;
  int wm = wid & 1, wn = wid >> 1;  // 2 (M) x 2 (N); wave tile 64x64
  int quad = lane >> 4, lr = lane & 15;

  // staging source: thread covers row i*32 + (tid>>3), chunk tid&7, inverse
  // XOR swizzle folded into the global k-offset.
  int rA = tid >> 3;                      // 0..31
  int ksw = ((tid & 7) ^ (rA & 7)) * 8;   // halves
  const unsigned short* WcE = Wc + (size_t)e * (2 * H_DIM) * D_DIM;
  const unsigned short* pA[4];
  const unsigned short* pB[4];
#pragma unroll
  for (int i = 0; i < 4; i++) {
    pA[i] = xh + (size_t)tokS[i * 32 + rA] * D_DIM + ksw;
    pB[i] = WcE + (size_t)(n0 + i * 32 + rA) * D_DIM + ksw;
  }
  int dstB = tid * 16;  // bytes; DMA i at +i*4096

  // fragment LDS bases. All frag rows = 16*a + lr -> row&7 == lr&7, so the
  // XOR-swizzle chunk term is lane-constant; frag/buf select is an imm.
  unsigned swz0 = (unsigned)(((0 * 4 + quad) ^ (lr & 7)) * 16);
  unsigned swz1 = (unsigned)(((1 * 4 + quad) ^ (lr & 7)) * 16);
  unsigned ldsA = ldsaddr(&As[0][0]);
  unsigned ldsB = ldsaddr(&Bs[0][0]);
  unsigned aA0 = ldsA + (unsigned)(wm * 8192 + lr * 128) + swz0;
  unsigned aA1 = ldsA + (unsigned)(wm * 8192 + lr * 128) + swz1;
  unsigned bB0 = ldsB + (unsigned)(wn * 8192 + lr * 128) + swz0;
  unsigned bB1 = ldsB + (unsigned)(wn * 8192 + lr * 128) + swz1;

  f4v acc[4][4];  // 64 AGPR
#pragma unroll
  for (int m = 0; m < 4; m++)
#pragma unroll
    for (int n = 0; n < 4; n++) acc[m][n] = (f4v){0.f, 0.f, 0.f, 0.f};

  // prologue: stage tile 0 into buf 0
  STG8(0);
#pragma unroll
  for (int i = 0; i < 4; i++) { pA[i] += BK; pB[i] += BK; }
  VMW(0);
  PH_BAR();

  h8v af[4][2], bf[4][2];

  // tiles 0..13 (cb compile-time via x2 unroll), each stages tile kt+1
  for (int it = 0; it < 7; ++it) {
    TILE128(0, 1);
    TILE128(1, 1);
  }
  TILE128(0, 1);  // tile 14, stages tile 15 into buf 1
  TILE128(1, 0);  // tile 15, no staging, no trailing barrier cost

  // epilogue: B-frag fn pairs (0,1) and (2,3) are (v,g) of the SAME 16 h
  // (16-granular interleave). C/D: col = lr, row = quad*4 + reg [m89/m91].
  // h = (n_global>>5)*16 + (n_global&15) -> hb = nt_*64 + wn*32 + p*16 + lr.
  int hb = nt_ * 64 + wn * 32 + lr;
#pragma unroll
  for (int m = 0; m < 4; m++) {
    int rb = wm * 64 + m * 16 + quad * 4;
#pragma unroll
    for (int r2 = 0; r2 < 4; r2++) {
      int rr = rb + r2;
      float sc = scS[rr];
      if (USE_PARTIAL) {
        _Float16* pr = partial + (size_t)(e * CAP + m0 + rr) * H_DIM;
#pragma unroll
        for (int p = 0; p < 2; p++) {
          float v = acc[m][2 * p][r2];
          float g = acc[m][2 * p + 1][r2];
          pr[hb + p * 16] = (_Float16)(v * sc / (1.0f + __expf(-g)));
        }
      } else {
        int tok = tokS[rr];
#pragma unroll
        for (int p = 0; p < 2; p++) {
          float v = acc[m][2 * p][r2];
          float g = acc[m][2 * p + 1][r2];
          atomicAdd(&out[(size_t)tok * H_DIM + hb + p * 16],
                    v * sc / (1.0f + __expf(-g)));
        }
      }
    }
  }
}

// ---------------- phase 3: gather (out[b] = partial[s0] + partial[s1]) ----------
__global__ __launch_bounds__(256) void gather_kernel(
    const _Float16* __restrict__ partial, const int* __restrict__ slotOf,
    float* __restrict__ out) {
  int b = blockIdx.x * 2 + (threadIdx.x >> 7);  // 2 tokens/block
  int t = threadIdx.x & 127;                     // 8 halves per thread
  int s0 = slotOf[b * 2], s1 = slotOf[b * 2 + 1];
  if ((unsigned)s0 >= E_NUM * CAP) s0 = 0;  // poison guard (overflow ~impossible)
  if ((unsigned)s1 >= E_NUM * CAP) s1 = 0;
  h8v a = ((const h8v*)(partial + (size_t)s0 * H_DIM))[t];
  h8v c = ((const h8v*)(partial + (size_t)s1 * H_DIM))[t];
  float4 o0, o1;
  o0.x = (float)a[0] + (float)c[0];
  o0.y = (float)a[1] + (float)c[1];
  o0.z = (float)a[2] + (float)c[2];
  o0.w = (float)a[3] + (float)c[3];
  o1.x = (float)a[4] + (float)c[4];
  o1.y = (float)a[5] + (float)c[5];
  o1.z = (float)a[6] + (float)c[6];
  o1.w = (float)a[7] + (float)c[7];
  float4* op = (float4*)(out + (size_t)b * H_DIM);
  op[t * 2] = o0;
  op[t * 2 + 1] = o1;
}

extern "C" void kernel_launch(void* const* d_in, const int* in_sizes, int n_in,
                              void* d_out, int out_size, void* d_ws, size_t ws_size,
                              hipStream_t stream) {
  const float* x = (const float*)d_in[0];
  const float* Wv = (const float*)d_in[1];
  const float* Wg = (const float*)d_in[2];
  const float* gw = (const float*)d_in[3];
  const float* gb = (const float*)d_in[4];
  float* out = (float*)d_out;
  const int B = in_sizes[0] / D_DIM;  // 16384

  char* ws = (char*)d_ws;
  unsigned short* xh = (unsigned short*)ws;                       // 32 MB
  size_t off = (size_t)B * D_DIM * 2;
  unsigned short* Wc = (unsigned short*)(ws + off);               // 32 MB (interleaved v/g)
  off += (size_t)E_NUM * (2 * H_DIM) * D_DIM * 2;
  int* counts = (int*)(ws + off);                                 // 8 padded counters
  off += 4096;
  int* bucket = (int*)(ws + off);                                 // E*CAP ints
  off += (size_t)E_NUM * CAP * 4;
  float* scoreB = (float*)(ws + off);                             // E*CAP floats
  off += (size_t)E_NUM * CAP * 4;
  int* slotOf = (int*)(ws + off);                                 // B*2 ints
  off += (size_t)B * 2 * 4;
  _Float16* partial = (_Float16*)(ws + off);                      // E*CAP*H fp16 = 80 MB
  size_t need = off + (size_t)E_NUM * CAP * H_DIM * 2;
  bool use_partial = ws_size >= need;

  hipMemsetAsync(counts, 0, 4096, stream);
  if (!use_partial) hipMemsetAsync(d_out, 0, (size_t)out_size * 4, stream);

  router_kernel<<<B / RT_TOK, 256, 0, stream>>>(
      (const float4*)x, (const float4*)gw, gb, counts, bucket, scoreB, slotOf,
      (ushort4*)xh, B);
  transpose_w_kernel<<<dim3(H_DIM / 64, D_DIM / 64, 2 * E_NUM), 256, 0, stream>>>(
      Wv, Wg, Wc);
  if (use_partial) {
    moe_gemm_kernel<true><<<E_NUM * MT * NTL, 256, 0, stream>>>(
        xh, Wc, counts, bucket, scoreB, partial, out, B);
    gather_kernel<<<B / 2, 256, 0, stream>>>(partial, slotOf, out);
  } else {
    moe_gemm_kernel<false><<<E_NUM * MT * NTL, 256, 0, stream>>>(
        xh, Wc, counts, bucket, scoreB, partial, out, B);
  }
}